// Round 10
// baseline (3164.932 us; speedup 1.0000x reference)
//
#include <hip/hip_runtime.h>
#include <hip/hip_bf16.h>

// Grouped Residual VQ: G=2, Q=8, K=1024, CD=256, DIM=1280 (DG=640), T=32768.
//
// Fast path: distance GEMM via bf16 3-term split MFMA; tokens with
// (second-best - best) < EPS get an exact f64 rescan of all 1024 codes.
// Score = ||c||^2 - 2 r.c (rn-invariant argmin). STE rounding replicated.
// quantized = h - res_final (computed in k_proj_out).
//
// k_rvq dataflow (this round): A (block's 128-token residual, bf16 hi/lo,
// 128 KB) staged into LDS ONCE per q; codebook streamed through a 2x8KB
// double-buffered window (128 phases/q = 16 code-chunks x 8 dim-chunks),
// raw s_barrier + counted vmcnt(1). Kills the 8x A re-read that made
// round 9 traffic-bound (4.1 GB/dispatch).

#define G 2
#define Q 8
#define KCODES 1024
#define CD 256
#define DIMV 1280
#define DG 640
#define T 32768
#define TM 128

#define WS_H      ((size_t)0)
#define WS_RES    (WS_H + (size_t)G*T*CD)
#define WS_CNORM  (WS_RES + (size_t)G*T*CD)
#define WS_CN64   (WS_CNORM + (size_t)G*Q*KCODES)
#define WS_LPARTD (WS_CN64 + (size_t)2*G*Q*KCODES)

#define OUT_IDX   ((size_t)T*DIMV)
#define OUT_LOSS  (OUT_IDX + (size_t)G*T*Q)

#define EPS_REFINE 2e-3f

typedef __attribute__((ext_vector_type(8))) short s16x8;
typedef __attribute__((ext_vector_type(4))) float f32x4;

static __device__ __forceinline__ unsigned short f2bf(float v) {
    __hip_bfloat16 b = __float2bfloat16(v);
    return *(unsigned short*)&b;
}
static __device__ __forceinline__ float bf2f(unsigned short u) {
    __hip_bfloat16 b = *(__hip_bfloat16*)&u;
    return __bfloat162float(b);
}

static __device__ __forceinline__ void gl_lds16(const void* g, void* l) {
    __builtin_amdgcn_global_load_lds(
        (const __attribute__((address_space(1))) unsigned int*)g,
        (__attribute__((address_space(3))) unsigned int*)l, 16, 0, 0);
}

__device__ __forceinline__ float np_half_sumsq(const float4* __restrict__ p) {
    float4 a = p[0], b = p[1];
    float r0=a.x*a.x, r1=a.y*a.y, r2=a.z*a.z, r3=a.w*a.w;
    float r4=b.x*b.x, r5=b.y*b.y, r6=b.z*b.z, r7=b.w*b.w;
#pragma unroll
    for (int i = 1; i < 16; i++) {
        a = p[2*i]; b = p[2*i+1];
        r0 += a.x*a.x; r1 += a.y*a.y; r2 += a.z*a.z; r3 += a.w*a.w;
        r4 += b.x*b.x; r5 += b.y*b.y; r6 += b.z*b.z; r7 += b.w*b.w;
    }
    return ((r0+r1)+(r2+r3)) + ((r4+r5)+(r6+r7));
}

// ---------------- K1: codebook norms (f32 + exact f64) ----------------
__global__ void k_norms(const float* __restrict__ cb, float* __restrict__ ws) {
    int r = blockIdx.x * 256 + threadIdx.x;
    const float4* row = (const float4*)(cb + (size_t)r * CD);
    ws[WS_CNORM + r] = np_half_sumsq(row) + np_half_sumsq(row + 32);
    double s0=0, s1=0, s2=0, s3=0;
#pragma unroll 8
    for (int e = 0; e < 64; e++) {
        float4 v = row[e];
        s0 = fma((double)v.x,(double)v.x,s0); s1 = fma((double)v.y,(double)v.y,s1);
        s2 = fma((double)v.z,(double)v.z,s2); s3 = fma((double)v.w,(double)v.w,s3);
    }
    ((double*)(ws + WS_CN64))[r] = (s0+s1)+(s2+s3);
}

// ---------------- K1b: codebook bf16 hi/lo split ----------------
__global__ void k_split(const float* __restrict__ cb, short* __restrict__ cbh,
                        short* __restrict__ cbl) {
    size_t i = ((size_t)blockIdx.x * 256 + threadIdx.x) * 4;
    float4 v = *(const float4*)(cb + i);
    unsigned short h0=f2bf(v.x), h1=f2bf(v.y), h2=f2bf(v.z), h3=f2bf(v.w);
    *(short4*)(cbh + i) = make_short4((short)h0,(short)h1,(short)h2,(short)h3);
    *(short4*)(cbl + i) = make_short4((short)f2bf(v.x - bf2f(h0)), (short)f2bf(v.y - bf2f(h1)),
                                      (short)f2bf(v.z - bf2f(h2)), (short)f2bf(v.w - bf2f(h3)));
}

// ---------------- K2: input projection h = x_g @ Win_g^T + bin (+ bf16 split) ----------------
__global__ __launch_bounds__(256) void k_proj_in(const float* __restrict__ x,
                                                 const float* __restrict__ Win,
                                                 const float* __restrict__ bin,
                                                 float* __restrict__ ws,
                                                 short* __restrict__ resh,
                                                 short* __restrict__ resl) {
    __shared__ float As[32][65];
    __shared__ float Bs[32][65];
    const int g  = blockIdx.z;
    const int t0 = blockIdx.x * 64;
    const int c0 = blockIdx.y * 64;
    const int tid = threadIdx.x;
    const int tx = tid & 15, ty = tid >> 4;
    float acc[4][4] = {};
    const float* Ab = x + (size_t)t0 * DIMV + (size_t)g * DG;
    const float* Bb = Win + (size_t)g * CD * DG + (size_t)c0 * DG;

    for (int k0 = 0; k0 < DG; k0 += 32) {
        __syncthreads();
#pragma unroll
        for (int j = 0; j < 8; j++) {
            int lin = j * 256 + tid;
            int k = lin & 31, r = lin >> 5;
            As[k][r] = Ab[(size_t)r * DIMV + k0 + k];
            Bs[k][r] = Bb[(size_t)r * DG + k0 + k];
        }
        __syncthreads();
#pragma unroll
        for (int k = 0; k < 32; k++) {
            float a[4], b[4];
#pragma unroll
            for (int i = 0; i < 4; i++) a[i] = As[k][ty + 16 * i];
#pragma unroll
            for (int j = 0; j < 4; j++) b[j] = Bs[k][tx + 16 * j];
#pragma unroll
            for (int i = 0; i < 4; i++)
#pragma unroll
                for (int j = 0; j < 4; j++) acc[i][j] = fmaf(a[i], b[j], acc[i][j]);
        }
    }
#pragma unroll
    for (int i = 0; i < 4; i++) {
        int t = t0 + ty + 16 * i;
        size_t roff = ((size_t)g * T + t) * CD;
        float* hrow = ws + WS_H + roff;
#pragma unroll
        for (int j = 0; j < 4; j++) {
            int c = c0 + tx + 16 * j;
            float v = acc[i][j] + bin[g * CD + c];
            hrow[c] = v;
            unsigned short hb = f2bf(v);
            resh[roff + c] = (short)hb;
            resl[roff + c] = (short)f2bf(v - bf2f(hb));
        }
    }
}

// ---------------- K3: fused ResidualVQ (A-resident LDS, B-streamed) ----------------
// 512 threads = 8 waves (wy 0..3 x wx 0..1). Wave tile: 32 tokens x 32 codes
// per 64-code chunk. A: [plane][row 128][unit 32] s16x8, swizzle u^(row&31).
// B: [buf][plane][row 64][unit 4], swizzle u^(row&3). 128 phases/q.
__global__ __launch_bounds__(512, 2) void k_rvq(const float* __restrict__ cb,
                                                float* __restrict__ ws,
                                                float* __restrict__ out,
                                                short* __restrict__ resh,
                                                short* __restrict__ resl,
                                                const short* __restrict__ cbh,
                                                const short* __restrict__ cbl) {
    __shared__ s16x8 AsV[8192];        // 128 KB: plane*4096 + row*32 + u_phys
    __shared__ s16x8 BsV[2][512];      // 16 KB: pl*256 + row*4 + u_phys
    __shared__ float cnS[KCODES];
    __shared__ float mmv1[TM], mmv2[TM];
    __shared__ int   mmi[TM];
    __shared__ double lredD[8];

    const int g  = blockIdx.y;
    const int t0 = blockIdx.x * TM;
    const int tid = threadIdx.x;
    const int lane = tid & 63, l15 = lane & 15, l4 = lane >> 4;   // l4 in 0..3
    const int w = tid >> 6, wy = w >> 1, wx = w & 1;
    const int tx = tid & 15, ty = tid >> 4;                        // ty in 0..31
    const size_t gT = (size_t)g * T;
    float* hbuf = ws + WS_H;
    float* rbuf = ws + WS_RES;
    const float* cng = ws + WS_CNORM + (size_t)g * Q * KCODES;
    double* lpD = (double*)(ws + WS_LPARTD);

    // --- A staging geometry (16 gl_lds/thread/q), source pre-swizzled ---
    int aoff[16];
#pragma unroll
    for (int k = 0; k < 16; k++) {
        int row = (k & 7) * 16 + (tid >> 5);
        int uph = tid & 31;
        int ulg = uph ^ (row & 31);
        aoff[k] = (t0 + row) * CD + ulg * 8;    // element offset within group plane
    }
    // --- B staging geometry (1 gl_lds/thread/phase) ---
    const int bpl = tid >> 8;                   // 0: hi plane, 1: lo plane
    int brow = (tid & 255) >> 2;
    int bulg = (tid & 3) ^ (brow & 3);
    const int boff = brow * CD + bulg * 8;

    for (int q = 0; q < Q; q++) {
        const float* cnq = cng + (size_t)q * KCODES;
        const double* cn64q = (const double*)(ws + WS_CN64) + ((size_t)g * Q + q) * KCODES;
        const float* cqb = cb + ((size_t)g * Q + q) * KCODES * CD;
        const short* cbhq = cbh + ((size_t)g * Q + q) * KCODES * CD;
        const short* cblq = cbl + ((size_t)g * Q + q) * KCODES * CD;
        const float* rsrc = (q == 0) ? hbuf : rbuf;
        const short* rgh = resh + gT * CD;
        const short* rgl = resl + gT * CD;
        const short* bsrc = bpl ? cblq : cbhq;

        cnS[tid] = cnq[tid];
        cnS[512 + tid] = cnq[512 + tid];
        // stage A (once per q) + B chunk 0
#pragma unroll
        for (int k = 0; k < 16; k++)
            gl_lds16((k >= 8 ? rgl : rgh) + aoff[k], &AsV[k * 512 + w * 64]);
        gl_lds16(bsrc + boff, &BsV[0][w * 64]);
        __syncthreads();                        // drains vmcnt: A + B0 ready

        float tv1[8], tv2[8]; int tix[8];
#pragma unroll
        for (int e = 0; e < 8; e++) { tv1[e] = 3.4e38f; tv2[e] = 3.4e38f; tix[e] = 0x7fffffff; }

        f32x4 acc[2][2];
#pragma unroll
        for (int i = 0; i < 2; i++)
#pragma unroll
            for (int j = 0; j < 2; j++) acc[i][j] = (f32x4){0.f, 0.f, 0.f, 0.f};

        for (int p = 0; p < 128; p++) {
            const int buf = p & 1, cc = p >> 3, dc = p & 7;
            __builtin_amdgcn_s_barrier();       // all waves done reading buf[(p+1)&1]
            if (p + 1 < 128) {
                const int np = p + 1;
                gl_lds16(bsrc + (np >> 3) * (64 * CD) + (np & 7) * 32 + boff,
                         &BsV[np & 1][w * 64]);
                asm volatile("s_waitcnt vmcnt(1)" ::: "memory");  // B(p) landed
            } else {
                asm volatile("s_waitcnt vmcnt(0)" ::: "memory");
            }
            __builtin_amdgcn_s_barrier();
            __builtin_amdgcn_sched_barrier(0);

            s16x8 ah[2], al[2];
#pragma unroll
            for (int ti = 0; ti < 2; ti++) {
                int r = wy * 32 + ti * 16 + l15;
                int u = (dc * 4 + l4) ^ (r & 31);
                ah[ti] = AsV[r * 32 + u];
                al[ti] = AsV[4096 + r * 32 + u];
            }
#pragma unroll
            for (int tj = 0; tj < 2; tj++) {
                int r = wx * 32 + tj * 16 + l15;
                int u = l4 ^ (r & 3);
                s16x8 bh = BsV[buf][r * 4 + u];
                s16x8 bl = BsV[buf][256 + r * 4 + u];
#pragma unroll
                for (int ti = 0; ti < 2; ti++) {
                    acc[ti][tj] = __builtin_amdgcn_mfma_f32_16x16x32_bf16(ah[ti], bh, acc[ti][tj], 0, 0, 0);
                    acc[ti][tj] = __builtin_amdgcn_mfma_f32_16x16x32_bf16(ah[ti], bl, acc[ti][tj], 0, 0, 0);
                    acc[ti][tj] = __builtin_amdgcn_mfma_f32_16x16x32_bf16(al[ti], bh, acc[ti][tj], 0, 0, 0);
                }
            }
            if (dc == 7) {      // score chunk cc: vv = ||c||^2 - 2 r.c
#pragma unroll
                for (int tj = 0; tj < 2; tj++) {
                    int c = cc * 64 + wx * 32 + tj * 16 + l15;
                    float cnv = cnS[c];
#pragma unroll
                    for (int e = 0; e < 8; e++) {
                        float vv = fmaf(-2.f, acc[e >> 2][tj][e & 3], cnv);
                        if (vv < tv1[e]) { tv2[e] = tv1[e]; tv1[e] = vv; tix[e] = c; }
                        else tv2[e] = fminf(tv2[e], vv);
                    }
                }
#pragma unroll
                for (int i = 0; i < 2; i++)
#pragma unroll
                    for (int j = 0; j < 2; j++) acc[i][j] = (f32x4){0.f, 0.f, 0.f, 0.f};
            }
        }
        __syncthreads();

        // ---- cross-lane two-min butterfly (16 code-columns) ----
#pragma unroll
        for (int e = 0; e < 8; e++) {
            float v1 = tv1[e], v2 = tv2[e]; int i1 = tix[e];
#pragma unroll
            for (int m = 1; m < 16; m <<= 1) {
                float w1 = __shfl_xor(v1, m, 64);
                float w2 = __shfl_xor(v2, m, 64);
                int   j1 = __shfl_xor(i1, m, 64);
                if (w1 < v1)       { v2 = fminf(v1, w2); v1 = w1; i1 = j1; }
                else if (w1 == v1) { v2 = v1; if (j1 < i1) i1 = j1; }
                else               { v2 = fminf(v2, w1); }
            }
            tv1[e] = v1; tv2[e] = v2; tix[e] = i1;
        }
        // ---- cross-wave (wx halves) merge via LDS ----
        if (wx == 0 && l15 == 0) {
#pragma unroll
            for (int e = 0; e < 8; e++) {
                int tok = wy * 32 + (e >> 2) * 16 + l4 * 4 + (e & 3);
                mmv1[tok] = tv1[e]; mmv2[tok] = tv2[e]; mmi[tok] = tix[e];
            }
        }
        __syncthreads();
        if (wx == 1 && l15 == 0) {
#pragma unroll
            for (int e = 0; e < 8; e++) {
                int tok = wy * 32 + (e >> 2) * 16 + l4 * 4 + (e & 3);
                float a1 = mmv1[tok], a2 = mmv2[tok]; int ai = mmi[tok];
                float b1 = tv1[e], b2 = tv2[e]; int bi = tix[e];
                if (b1 < a1)       { a2 = fminf(a1, b2); a1 = b1; ai = bi; }
                else if (b1 == a1) { a2 = a1; if (bi < ai) ai = bi; }
                else               { a2 = fminf(a2, b1); }
                mmv1[tok] = a1; mmv2[tok] = a2; mmi[tok] = ai;
            }
        }
        __syncthreads();

        // ---- exact f64 refinement for near-tie tokens (rare) ----
        int besti[4];
#pragma unroll 1
        for (int i = 0; i < 4; i++) {
            int tok = ty + 32 * i;
            besti[i] = mmi[tok];
            if (!(mmv2[tok] - mmv1[tok] < EPS_REFINE)) continue;
            const float4* rp4 = (const float4*)(rsrc + (gT + t0 + tok) * CD);
            double bv = 1e300; int bi = 0x7fffffff;
            for (int c = tx; c < KCODES; c += 16) {
                const float4* cp4 = (const float4*)(cqb + (size_t)c * CD);
                double a0=0, a1=0, a2=0, a3=0;
#pragma unroll 4
                for (int e = 0; e < 64; e++) {
                    float4 cv = cp4[e], rv = rp4[e];
                    a0 = fma((double)rv.x,(double)cv.x,a0); a1 = fma((double)rv.y,(double)cv.y,a1);
                    a2 = fma((double)rv.z,(double)cv.z,a2); a3 = fma((double)rv.w,(double)cv.w,a3);
                }
                double dd = fma(-2.0, (a0+a1)+(a2+a3), cn64q[c]);
                if (dd < bv) { bv = dd; bi = c; }
            }
#pragma unroll
            for (int m = 1; m < 16; m <<= 1) {
                double ov = __shfl_xor(bv, m, 64);
                int    oi = __shfl_xor(bi, m, 64);
                if (ov < bv || (ov == bv && oi < bi)) { bv = ov; bi = oi; }
            }
            besti[i] = bi;
        }

        // ---- idx out ----
        if (tx == 0) {
#pragma unroll
            for (int i = 0; i < 4; i++)
                out[OUT_IDX + (gT + t0 + ty + 32 * i) * Q + q] = (float)besti[i];
        }

        // ---- STE epilogue: res rounding-replicated; bf16 split fused ----
        double lacc = 0.0;
#pragma unroll
        for (int i = 0; i < 4; i++) {
            int t = ty + 32 * i;
            size_t off = (gT + t0 + t) * CD;
            const float4* cp = (const float4*)(cqb + (size_t)besti[i] * CD) + tx * 4;
            const float4* rp = (const float4*)(rsrc + off) + tx * 4;
            float4* wp = (float4*)(rbuf + off) + tx * 4;
            short* rhp = resh + off + tx * 16;
            short* rlp = resl + off + tx * 16;
#pragma unroll
            for (int e = 0; e < 4; e++) {
                float4 c4 = cp[e], r4 = rp[e];
                float4 res4;
                float tt, qq, rr;
                tt = __fsub_rn(c4.x, r4.x); qq = __fadd_rn(r4.x, tt); rr = __fsub_rn(r4.x, qq);
                lacc += (double)rr * rr; res4.x = rr;
                tt = __fsub_rn(c4.y, r4.y); qq = __fadd_rn(r4.y, tt); rr = __fsub_rn(r4.y, qq);
                lacc += (double)rr * rr; res4.y = rr;
                tt = __fsub_rn(c4.z, r4.z); qq = __fadd_rn(r4.z, tt); rr = __fsub_rn(r4.z, qq);
                lacc += (double)rr * rr; res4.z = rr;
                tt = __fsub_rn(c4.w, r4.w); qq = __fadd_rn(r4.w, tt); rr = __fsub_rn(r4.w, qq);
                lacc += (double)rr * rr; res4.w = rr;
                wp[e] = res4;
                unsigned short h0=f2bf(res4.x), h1=f2bf(res4.y), h2=f2bf(res4.z), h3=f2bf(res4.w);
                *(short4*)(rhp + e*4) = make_short4((short)h0,(short)h1,(short)h2,(short)h3);
                *(short4*)(rlp + e*4) = make_short4((short)f2bf(res4.x - bf2f(h0)),
                                                    (short)f2bf(res4.y - bf2f(h1)),
                                                    (short)f2bf(res4.z - bf2f(h2)),
                                                    (short)f2bf(res4.w - bf2f(h3)));
            }
        }
        // deterministic loss partial (f64)
#pragma unroll
        for (int m = 1; m < 64; m <<= 1) lacc += __shfl_xor(lacc, m, 64);
        __syncthreads();
        if ((tid & 63) == 0) lredD[tid >> 6] = lacc;
        __syncthreads();
        if (tid == 0)
            lpD[((size_t)g * Q + q) * 256 + blockIdx.x] =
                ((lredD[0] + lredD[1]) + (lredD[2] + lredD[3])) +
                ((lredD[4] + lredD[5]) + (lredD[6] + lredD[7]));
        __syncthreads();   // drains stores: next q's gl_lds reads resh/resl safely
    }
}

// ---------------- K4: output projection out = (h - res) @ Wout_g^T + bout ----------------
__global__ __launch_bounds__(256) void k_proj_out(const float* __restrict__ ws,
                                                  const float* __restrict__ Wout,
                                                  const float* __restrict__ bout,
                                                  float* __restrict__ out) {
    __shared__ float As[32][65];
    __shared__ float Bs[32][65];
    const int g  = blockIdx.z;
    const int t0 = blockIdx.x * 64;
    const int d0 = blockIdx.y * 64;
    const int tid = threadIdx.x;
    const int tx = tid & 15, ty = tid >> 4;
    float acc[4][4] = {};
    const float* Ah = ws + WS_H + ((size_t)g * T + t0) * CD;
    const float* Ar = ws + WS_RES + ((size_t)g * T + t0) * CD;
    const float* Bb = Wout + (size_t)g * DG * CD + (size_t)d0 * CD;

    for (int k0 = 0; k0 < CD; k0 += 32) {
        __syncthreads();
#pragma unroll
        for (int j = 0; j < 8; j++) {
            int lin = j * 256 + tid;
            int k = lin & 31, r = lin >> 5;
            size_t o = (size_t)r * CD + k0 + k;
            As[k][r] = Ah[o] - Ar[o];            // qout = h - res_final
            Bs[k][r] = Bb[o];
        }
        __syncthreads();
#pragma unroll
        for (int k = 0; k < 32; k++) {
            float a[4], b[4];
#pragma unroll
            for (int i = 0; i < 4; i++) a[i] = As[k][ty + 16 * i];
#pragma unroll
            for (int j = 0; j < 4; j++) b[j] = Bs[k][tx + 16 * j];
#pragma unroll
            for (int i = 0; i < 4; i++)
#pragma unroll
                for (int j = 0; j < 4; j++) acc[i][j] = fmaf(a[i], b[j], acc[i][j]);
        }
    }
#pragma unroll
    for (int i = 0; i < 4; i++) {
        int t = t0 + ty + 16 * i;
#pragma unroll
        for (int j = 0; j < 4; j++) {
            int d = d0 + tx + 16 * j;
            out[(size_t)t * DIMV + (size_t)g * DG + d] = acc[i][j] + bout[g * DG + d];
        }
    }
}

// ---------------- K5: deterministic loss reduction (f64 -> f32) ----------------
__global__ void k_loss(const float* __restrict__ ws, float* __restrict__ out) {
    int gq = blockIdx.x;
    const double* lpD = (const double*)(ws + WS_LPARTD);
    double v = lpD[(size_t)gq * 256 + threadIdx.x];
#pragma unroll
    for (int m = 1; m < 64; m <<= 1) v += __shfl_xor(v, m, 64);
    __shared__ double red[4];
    if ((threadIdx.x & 63) == 0) red[threadIdx.x >> 6] = v;
    __syncthreads();
    if (threadIdx.x == 0)
        out[OUT_LOSS + gq] =
            (float)(((red[0] + red[1]) + (red[2] + red[3])) * (1.0 / 8388608.0));
}

extern "C" void kernel_launch(void* const* d_in, const int* in_sizes, int n_in,
                              void* d_out, int out_size, void* d_ws, size_t ws_size,
                              hipStream_t stream) {
    const float* x    = (const float*)d_in[0];
    const float* Win  = (const float*)d_in[1];
    const float* bin  = (const float*)d_in[2];
    const float* Wout = (const float*)d_in[3];
    const float* bout = (const float*)d_in[4];
    const float* cb   = (const float*)d_in[5];
    float* out = (float*)d_out;
    float* ws  = (float*)d_ws;

    // bf16 hi/lo scratch in the not-yet-written quantized region of d_out:
    // 2*G*T*CD + 2*G*Q*K*CD bf16 = 25.2M f32-equiv < 41.9M f32 region.
    short* scr  = (short*)d_out;
    short* resh = scr;
    short* resl = scr + (size_t)G * T * CD;
    short* cbh  = scr + (size_t)2 * G * T * CD;
    short* cbl  = cbh + (size_t)G * Q * KCODES * CD;

    hipLaunchKernelGGL(k_norms,    dim3(64),          dim3(256), 0, stream, cb, ws);
    hipLaunchKernelGGL(k_split,    dim3(4096),        dim3(256), 0, stream, cb, cbh, cbl);
    hipLaunchKernelGGL(k_proj_in,  dim3(T/64, 4, G),  dim3(256), 0, stream, x, Win, bin, ws, resh, resl);
    hipLaunchKernelGGL(k_rvq,      dim3(T/TM, G),     dim3(512), 0, stream, cb, ws, out, resh, resl, cbh, cbl);
    hipLaunchKernelGGL(k_proj_out, dim3(T/64, 10, G), dim3(256), 0, stream, ws, Wout, bout, out);
    hipLaunchKernelGGL(k_loss,     dim3(16),          dim3(256), 0, stream, ws, out);
}

// Round 11
// 2852.846 us; speedup vs baseline: 1.1094x; 1.1094x over previous
//
#include <hip/hip_runtime.h>
#include <hip/hip_bf16.h>

// Grouped Residual VQ: G=2, Q=8, K=1024, CD=256, DIM=1280 (DG=640), T=32768.
//
// k_rvq dataflow (round 11): TOKEN-STATIONARY REGISTERS. Each wave owns 32
// tokens; their bf16 hi/lo MFMA fragments (split on the fly from the f32
// residual) live in 128 VGPRs for the whole q-step. Only the codebook
// streams through LDS (64 codes x 32 dims x hi/lo = 8 KB, double-buffered,
// row-fastest layout -> conflict-free ds_read_b128), staged by
// global_load_lds + raw s_barrier + counted vmcnt(2).
// MFMA: C[code][token] = cb_tile x token_frags (same verified 16x16x32
// layouts as prior rounds, operands swapped). Per-lane two-min is scalar
// (lane&15 = token column). 3-term split (hh+hl+lh); EPS=2e-3 gate + exact
// f64 rescan; STE rounding chain replicated; quantized = h - res_final.

#define G 2
#define Q 8
#define KCODES 1024
#define CD 256
#define DIMV 1280
#define DG 640
#define T 32768
#define TM 128

#define WS_H      ((size_t)0)
#define WS_RES    (WS_H + (size_t)G*T*CD)
#define WS_CNORM  (WS_RES + (size_t)G*T*CD)
#define WS_CN64   (WS_CNORM + (size_t)G*Q*KCODES)
#define WS_LPARTD (WS_CN64 + (size_t)2*G*Q*KCODES)

#define OUT_IDX   ((size_t)T*DIMV)
#define OUT_LOSS  (OUT_IDX + (size_t)G*T*Q)

#define EPS_REFINE 2e-3f

typedef __attribute__((ext_vector_type(8))) short s16x8;
typedef __attribute__((ext_vector_type(4))) float f32x4;

static __device__ __forceinline__ unsigned short f2bf(float v) {
    __hip_bfloat16 b = __float2bfloat16(v);
    return *(unsigned short*)&b;
}
static __device__ __forceinline__ float bf2f(unsigned short u) {
    __hip_bfloat16 b = *(__hip_bfloat16*)&u;
    return __bfloat162float(b);
}

static __device__ __forceinline__ void gl_lds16(const void* g, void* l) {
    __builtin_amdgcn_global_load_lds(
        (const __attribute__((address_space(1))) unsigned int*)g,
        (__attribute__((address_space(3))) unsigned int*)l, 16, 0, 0);
}

__device__ __forceinline__ float np_half_sumsq(const float4* __restrict__ p) {
    float4 a = p[0], b = p[1];
    float r0=a.x*a.x, r1=a.y*a.y, r2=a.z*a.z, r3=a.w*a.w;
    float r4=b.x*b.x, r5=b.y*b.y, r6=b.z*b.z, r7=b.w*b.w;
#pragma unroll
    for (int i = 1; i < 16; i++) {
        a = p[2*i]; b = p[2*i+1];
        r0 += a.x*a.x; r1 += a.y*a.y; r2 += a.z*a.z; r3 += a.w*a.w;
        r4 += b.x*b.x; r5 += b.y*b.y; r6 += b.z*b.z; r7 += b.w*b.w;
    }
    return ((r0+r1)+(r2+r3)) + ((r4+r5)+(r6+r7));
}

// ---------------- K1: codebook norms (f32 + exact f64) ----------------
__global__ void k_norms(const float* __restrict__ cb, float* __restrict__ ws) {
    int r = blockIdx.x * 256 + threadIdx.x;
    const float4* row = (const float4*)(cb + (size_t)r * CD);
    ws[WS_CNORM + r] = np_half_sumsq(row) + np_half_sumsq(row + 32);
    double s0=0, s1=0, s2=0, s3=0;
#pragma unroll 8
    for (int e = 0; e < 64; e++) {
        float4 v = row[e];
        s0 = fma((double)v.x,(double)v.x,s0); s1 = fma((double)v.y,(double)v.y,s1);
        s2 = fma((double)v.z,(double)v.z,s2); s3 = fma((double)v.w,(double)v.w,s3);
    }
    ((double*)(ws + WS_CN64))[r] = (s0+s1)+(s2+s3);
}

// ---------------- K1b: codebook bf16 hi/lo split ----------------
__global__ void k_split(const float* __restrict__ cb, short* __restrict__ cbh,
                        short* __restrict__ cbl) {
    size_t i = ((size_t)blockIdx.x * 256 + threadIdx.x) * 4;
    float4 v = *(const float4*)(cb + i);
    unsigned short h0=f2bf(v.x), h1=f2bf(v.y), h2=f2bf(v.z), h3=f2bf(v.w);
    *(short4*)(cbh + i) = make_short4((short)h0,(short)h1,(short)h2,(short)h3);
    *(short4*)(cbl + i) = make_short4((short)f2bf(v.x - bf2f(h0)), (short)f2bf(v.y - bf2f(h1)),
                                      (short)f2bf(v.z - bf2f(h2)), (short)f2bf(v.w - bf2f(h3)));
}

// ---------------- K2: input projection h = x_g @ Win_g^T + bin ----------------
__global__ __launch_bounds__(256) void k_proj_in(const float* __restrict__ x,
                                                 const float* __restrict__ Win,
                                                 const float* __restrict__ bin,
                                                 float* __restrict__ ws) {
    __shared__ float As[32][65];
    __shared__ float Bs[32][65];
    const int g  = blockIdx.z;
    const int t0 = blockIdx.x * 64;
    const int c0 = blockIdx.y * 64;
    const int tid = threadIdx.x;
    const int tx = tid & 15, ty = tid >> 4;
    float acc[4][4] = {};
    const float* Ab = x + (size_t)t0 * DIMV + (size_t)g * DG;
    const float* Bb = Win + (size_t)g * CD * DG + (size_t)c0 * DG;

    for (int k0 = 0; k0 < DG; k0 += 32) {
        __syncthreads();
#pragma unroll
        for (int j = 0; j < 8; j++) {
            int lin = j * 256 + tid;
            int k = lin & 31, r = lin >> 5;
            As[k][r] = Ab[(size_t)r * DIMV + k0 + k];
            Bs[k][r] = Bb[(size_t)r * DG + k0 + k];
        }
        __syncthreads();
#pragma unroll
        for (int k = 0; k < 32; k++) {
            float a[4], b[4];
#pragma unroll
            for (int i = 0; i < 4; i++) a[i] = As[k][ty + 16 * i];
#pragma unroll
            for (int j = 0; j < 4; j++) b[j] = Bs[k][tx + 16 * j];
#pragma unroll
            for (int i = 0; i < 4; i++)
#pragma unroll
                for (int j = 0; j < 4; j++) acc[i][j] = fmaf(a[i], b[j], acc[i][j]);
        }
    }
#pragma unroll
    for (int i = 0; i < 4; i++) {
        int t = t0 + ty + 16 * i;
        float* hrow = ws + WS_H + ((size_t)g * T + t) * CD;
#pragma unroll
        for (int j = 0; j < 4; j++) {
            int c = c0 + tx + 16 * j;
            hrow[c] = acc[i][j] + bin[g * CD + c];
        }
    }
}

// ---------------- K3: fused ResidualVQ (token-stationary registers) ----------------
// 256 threads = 4 waves; wave owns 32 tokens (2 col-sets of 16).
// LDS codebook window: [plane 2][ku 4][code 64] s16x8, double-buffered.
__global__ __launch_bounds__(256, 2) void k_rvq(const float* __restrict__ cb,
                                                float* __restrict__ ws,
                                                float* __restrict__ out,
                                                const short* __restrict__ cbh,
                                                const short* __restrict__ cbl) {
    __shared__ s16x8 AsB[2][512];      // 16 KB total
    __shared__ float cnS[KCODES];
    __shared__ float mmv1[TM], mmv2[TM];
    __shared__ int   mmi[TM];
    __shared__ double lredD[4];

    const int g  = blockIdx.y;
    const int t0 = blockIdx.x * TM;
    const int tid = threadIdx.x;
    const int lane = tid & 63, l15 = lane & 15, l4 = lane >> 4;
    const int wv = tid >> 6;
    const int tx = tid & 15, ty = tid >> 4;
    const size_t gT = (size_t)g * T;
    float* hbuf = ws + WS_H;
    float* rbuf = ws + WS_RES;
    const float* cng = ws + WS_CNORM + (size_t)g * Q * KCODES;
    double* lpD = (double*)(ws + WS_LPARTD);

    // codebook staging geometry: wave wv covers units [wv*128, wv*128+128),
    // 2 gl_lds/wave; unit -> (plane, ku, code); LDS dest linear.
    int cpl[2]; size_t coff[2];
#pragma unroll
    for (int k = 0; k < 2; k++) {
        int unit = wv * 128 + k * 64 + lane;
        cpl[k] = unit >> 8;
        coff[k] = (size_t)(unit & 63) * CD + (size_t)(((unit >> 6) & 3) * 8);
    }

    for (int q = 0; q < Q; q++) {
        const float* cnq = cng + (size_t)q * KCODES;
        const double* cn64q = (const double*)(ws + WS_CN64) + ((size_t)g * Q + q) * KCODES;
        const float* cqb = cb + ((size_t)g * Q + q) * KCODES * CD;
        const short* cbhq = cbh + ((size_t)g * Q + q) * KCODES * CD;
        const short* cblq = cbl + ((size_t)g * Q + q) * KCODES * CD;
        const float* rsrc = (q == 0) ? hbuf : rbuf;

#pragma unroll
        for (int i = 0; i < 4; i++) cnS[i * 256 + tid] = cnq[i * 256 + tid];

        // ---- token fragments: load f32 residual, split to bf16 hi/lo in regs ----
        s16x8 bfh[2][8], bfl[2][8];
#pragma unroll
        for (int s = 0; s < 2; s++) {
            const float* base = rsrc + (gT + t0 + wv * 32 + s * 16 + l15) * CD + l4 * 8;
#pragma unroll
            for (int dc = 0; dc < 8; dc++) {
                float4 u0 = *(const float4*)(base + dc * 32);
                float4 u1 = *(const float4*)(base + dc * 32 + 4);
                float v[8] = {u0.x,u0.y,u0.z,u0.w,u1.x,u1.y,u1.z,u1.w};
                s16x8 fh, fl;
#pragma unroll
                for (int e = 0; e < 8; e++) {
                    unsigned short hb = f2bf(v[e]);
                    fh[e] = (short)hb;
                    fl[e] = (short)f2bf(v[e] - bf2f(hb));
                }
                bfh[s][dc] = fh; bfl[s][dc] = fl;
            }
        }
        // stage codebook chunk (cc=0, dc=0) into buf 0
#pragma unroll
        for (int k = 0; k < 2; k++)
            gl_lds16((cpl[k] ? cblq : cbhq) + coff[k], &AsB[0][wv * 128 + k * 64]);
        __syncthreads();                          // frags + chunk0 ready (vmcnt drained)

        float tv1[2], tv2[2]; int tix[2];
#pragma unroll
        for (int s = 0; s < 2; s++) { tv1[s] = 3.4e38f; tv2[s] = 3.4e38f; tix[s] = 0x7fffffff; }

        for (int cc = 0; cc < 16; cc++) {
            f32x4 acc[2][4];
#pragma unroll
            for (int s = 0; s < 2; s++)
#pragma unroll
                for (int t = 0; t < 4; t++) acc[s][t] = (f32x4){0.f, 0.f, 0.f, 0.f};

#pragma unroll
            for (int dc = 0; dc < 8; dc++) {
                __builtin_amdgcn_s_barrier();     // all waves done reading buf[dc^1]
                const int np = cc * 8 + dc + 1;
                if (np < 128) {
                    const int nb = (dc + 1) & 1;
                    const size_t add = (size_t)(np >> 3) * (64 * CD) + (size_t)((np & 7) * 32);
#pragma unroll
                    for (int k = 0; k < 2; k++)
                        gl_lds16((cpl[k] ? cblq : cbhq) + coff[k] + add,
                                 &AsB[nb][wv * 128 + k * 64]);
                    asm volatile("s_waitcnt vmcnt(2)" ::: "memory");  // current buf landed
                } else {
                    asm volatile("s_waitcnt vmcnt(0)" ::: "memory");
                }
                __builtin_amdgcn_s_barrier();
                __builtin_amdgcn_sched_barrier(0);

                const int buf = dc & 1;
#pragma unroll
                for (int t = 0; t < 4; t++) {
                    int idx = l4 * 64 + t * 16 + l15;
                    s16x8 ch = AsB[buf][idx];            // codebook hi
                    s16x8 cl = AsB[buf][256 + idx];      // codebook lo
#pragma unroll
                    for (int s = 0; s < 2; s++) {
                        acc[s][t] = __builtin_amdgcn_mfma_f32_16x16x32_bf16(ch, bfh[s][dc], acc[s][t], 0, 0, 0);
                        acc[s][t] = __builtin_amdgcn_mfma_f32_16x16x32_bf16(ch, bfl[s][dc], acc[s][t], 0, 0, 0);
                        acc[s][t] = __builtin_amdgcn_mfma_f32_16x16x32_bf16(cl, bfh[s][dc], acc[s][t], 0, 0, 0);
                    }
                }
            }
            // ---- score chunk cc: vv = ||c||^2 - 2 r.c ; per-lane scalar two-min ----
#pragma unroll
            for (int s = 0; s < 2; s++)
#pragma unroll
                for (int t = 0; t < 4; t++)
#pragma unroll
                    for (int r = 0; r < 4; r++) {
                        int c = cc * 64 + t * 16 + l4 * 4 + r;
                        float vv = fmaf(-2.f, acc[s][t][r], cnS[c]);
                        if (vv < tv1[s])       { tv2[s] = tv1[s]; tv1[s] = vv; tix[s] = c; }
                        else if (vv == tv1[s]) { tv2[s] = tv1[s]; if (c < tix[s]) tix[s] = c; }
                        else if (vv < tv2[s])  { tv2[s] = vv; }
                    }
        }

        // ---- merge the 4 same-token lanes (strides 16, 32), write per-token mm ----
#pragma unroll
        for (int s = 0; s < 2; s++) {
            float v1 = tv1[s], v2 = tv2[s]; int i1 = tix[s];
#pragma unroll
            for (int m = 16; m < 64; m <<= 1) {
                float w1 = __shfl_xor(v1, m, 64);
                float w2 = __shfl_xor(v2, m, 64);
                int   j1 = __shfl_xor(i1, m, 64);
                if (w1 < v1)       { v2 = fminf(v1, w2); v1 = w1; i1 = j1; }
                else if (w1 == v1) { v2 = v1; if (j1 < i1) i1 = j1; }
                else               { v2 = fminf(v2, w1); }
            }
            if (lane < 16) {
                int tok = wv * 32 + s * 16 + lane;
                mmv1[tok] = v1; mmv2[tok] = v2; mmi[tok] = i1;
            }
        }
        __syncthreads();

        // ---- exact f64 refinement for near-tie tokens (rare) ----
        int besti[8];
#pragma unroll 1
        for (int i = 0; i < 8; i++) {
            int tok = ty + 16 * i;
            besti[i] = mmi[tok];
            if (!(mmv2[tok] - mmv1[tok] < EPS_REFINE)) continue;
            const float4* rp4 = (const float4*)(rsrc + (gT + t0 + tok) * CD);
            double bv = 1e300; int bi = 0x7fffffff;
            for (int c = tx; c < KCODES; c += 16) {
                const float4* cp4 = (const float4*)(cqb + (size_t)c * CD);
                double a0=0, a1=0, a2=0, a3=0;
#pragma unroll 4
                for (int e = 0; e < 64; e++) {
                    float4 cv = cp4[e], rv = rp4[e];
                    a0 = fma((double)rv.x,(double)cv.x,a0); a1 = fma((double)rv.y,(double)cv.y,a1);
                    a2 = fma((double)rv.z,(double)cv.z,a2); a3 = fma((double)rv.w,(double)cv.w,a3);
                }
                double dd = fma(-2.0, (a0+a1)+(a2+a3), cn64q[c]);
                if (dd < bv) { bv = dd; bi = c; }
            }
#pragma unroll
            for (int m = 1; m < 16; m <<= 1) {
                double ov = __shfl_xor(bv, m, 64);
                int    oi = __shfl_xor(bi, m, 64);
                if (ov < bv || (ov == bv && oi < bi)) { bv = ov; bi = oi; }
            }
            besti[i] = bi;
        }

        // ---- idx out ----
        if (tx == 0) {
#pragma unroll
            for (int i = 0; i < 8; i++)
                out[OUT_IDX + (gT + t0 + ty + 16 * i) * Q + q] = (float)besti[i];
        }

        // ---- STE epilogue: res rounding-replicated (no resh/resl, no qout) ----
        double lacc = 0.0;
#pragma unroll
        for (int i = 0; i < 8; i++) {
            int t = ty + 16 * i;
            size_t off = (gT + t0 + t) * CD;
            const float4* cp = (const float4*)(cqb + (size_t)besti[i] * CD) + tx * 4;
            const float4* rp = (const float4*)(rsrc + off) + tx * 4;
            float4* wp = (float4*)(rbuf + off) + tx * 4;
#pragma unroll
            for (int e = 0; e < 4; e++) {
                float4 c4 = cp[e], r4 = rp[e];
                float4 res4;
                float tt, qq, rr;
                tt = __fsub_rn(c4.x, r4.x); qq = __fadd_rn(r4.x, tt); rr = __fsub_rn(r4.x, qq);
                lacc += (double)rr * rr; res4.x = rr;
                tt = __fsub_rn(c4.y, r4.y); qq = __fadd_rn(r4.y, tt); rr = __fsub_rn(r4.y, qq);
                lacc += (double)rr * rr; res4.y = rr;
                tt = __fsub_rn(c4.z, r4.z); qq = __fadd_rn(r4.z, tt); rr = __fsub_rn(r4.z, qq);
                lacc += (double)rr * rr; res4.z = rr;
                tt = __fsub_rn(c4.w, r4.w); qq = __fadd_rn(r4.w, tt); rr = __fsub_rn(r4.w, qq);
                lacc += (double)rr * rr; res4.w = rr;
                wp[e] = res4;
            }
        }
        // deterministic loss partial (f64)
#pragma unroll
        for (int m = 1; m < 64; m <<= 1) lacc += __shfl_xor(lacc, m, 64);
        __syncthreads();
        if ((tid & 63) == 0) lredD[tid >> 6] = lacc;
        __syncthreads();
        if (tid == 0)
            lpD[((size_t)g * Q + q) * 256 + blockIdx.x] =
                ((lredD[0] + lredD[1]) + (lredD[2] + lredD[3]));
        __syncthreads();   // drains rbuf stores before next q's fragment loads
    }
}

// ---------------- K4: output projection out = (h - res) @ Wout_g^T + bout ----------------
__global__ __launch_bounds__(256) void k_proj_out(const float* __restrict__ ws,
                                                  const float* __restrict__ Wout,
                                                  const float* __restrict__ bout,
                                                  float* __restrict__ out) {
    __shared__ float As[32][65];
    __shared__ float Bs[32][65];
    const int g  = blockIdx.z;
    const int t0 = blockIdx.x * 64;
    const int d0 = blockIdx.y * 64;
    const int tid = threadIdx.x;
    const int tx = tid & 15, ty = tid >> 4;
    float acc[4][4] = {};
    const float* Ah = ws + WS_H + ((size_t)g * T + t0) * CD;
    const float* Ar = ws + WS_RES + ((size_t)g * T + t0) * CD;
    const float* Bb = Wout + (size_t)g * DG * CD + (size_t)d0 * CD;

    for (int k0 = 0; k0 < CD; k0 += 32) {
        __syncthreads();
#pragma unroll
        for (int j = 0; j < 8; j++) {
            int lin = j * 256 + tid;
            int k = lin & 31, r = lin >> 5;
            size_t o = (size_t)r * CD + k0 + k;
            As[k][r] = Ah[o] - Ar[o];            // qout = h - res_final
            Bs[k][r] = Bb[o];
        }
        __syncthreads();
#pragma unroll
        for (int k = 0; k < 32; k++) {
            float a[4], b[4];
#pragma unroll
            for (int i = 0; i < 4; i++) a[i] = As[k][ty + 16 * i];
#pragma unroll
            for (int j = 0; j < 4; j++) b[j] = Bs[k][tx + 16 * j];
#pragma unroll
            for (int i = 0; i < 4; i++)
#pragma unroll
                for (int j = 0; j < 4; j++) acc[i][j] = fmaf(a[i], b[j], acc[i][j]);
        }
    }
#pragma unroll
    for (int i = 0; i < 4; i++) {
        int t = t0 + ty + 16 * i;
#pragma unroll
        for (int j = 0; j < 4; j++) {
            int d = d0 + tx + 16 * j;
            out[(size_t)t * DIMV + (size_t)g * DG + d] = acc[i][j] + bout[g * DG + d];
        }
    }
}

// ---------------- K5: deterministic loss reduction (f64 -> f32) ----------------
__global__ void k_loss(const float* __restrict__ ws, float* __restrict__ out) {
    int gq = blockIdx.x;
    const double* lpD = (const double*)(ws + WS_LPARTD);
    double v = lpD[(size_t)gq * 256 + threadIdx.x];
#pragma unroll
    for (int m = 1; m < 64; m <<= 1) v += __shfl_xor(v, m, 64);
    __shared__ double red[4];
    if ((threadIdx.x & 63) == 0) red[threadIdx.x >> 6] = v;
    __syncthreads();
    if (threadIdx.x == 0)
        out[OUT_LOSS + gq] =
            (float)(((red[0] + red[1]) + (red[2] + red[3])) * (1.0 / 8388608.0));
}

extern "C" void kernel_launch(void* const* d_in, const int* in_sizes, int n_in,
                              void* d_out, int out_size, void* d_ws, size_t ws_size,
                              hipStream_t stream) {
    const float* x    = (const float*)d_in[0];
    const float* Win  = (const float*)d_in[1];
    const float* bin  = (const float*)d_in[2];
    const float* Wout = (const float*)d_in[3];
    const float* bout = (const float*)d_in[4];
    const float* cb   = (const float*)d_in[5];
    float* out = (float*)d_out;
    float* ws  = (float*)d_ws;

    // bf16 hi/lo codebook scratch in the not-yet-written quantized region of
    // d_out: 2*G*Q*K*CD bf16 = 4.2M f32-equiv << 41.9M f32 region.
    short* scr = (short*)d_out;
    short* cbh = scr;
    short* cbl = scr + (size_t)G * Q * KCODES * CD;

    hipLaunchKernelGGL(k_norms,    dim3(64),          dim3(256), 0, stream, cb, ws);
    hipLaunchKernelGGL(k_split,    dim3(4096),        dim3(256), 0, stream, cb, cbh, cbl);
    hipLaunchKernelGGL(k_proj_in,  dim3(T/64, 4, G),  dim3(256), 0, stream, x, Win, bin, ws);
    hipLaunchKernelGGL(k_rvq,      dim3(T/TM, G),     dim3(256), 0, stream, cb, ws, out, cbh, cbl);
    hipLaunchKernelGGL(k_proj_out, dim3(T/64, 10, G), dim3(256), 0, stream, ws, Wout, bout, out);
    hipLaunchKernelGGL(k_loss,     dim3(16),          dim3(256), 0, stream, ws, out);
}